// Round 26
// baseline (373.806 us; speedup 1.0000x reference)
//
#include <hip/hip_runtime.h>
#include <hip/hip_bf16.h>
#include <hip/hip_fp8.h>
#include <stdint.h>

// ---------------------------------------------------------------------------
// DeformableTransformerDecoderLayer: N=2, nf=5, Q=300, C=256, NH=8, d=32,
// NL=4, NP=4, DFF=1024. Levels (H,W): (100,150),(50,75),(25,38),(13,19),
// starts {0,15000,18750,19700}, LIN=19947.
// R24 build (335.9us) with gemm_val narrowed to BN=128 (BM=64, FM=2, FN=4):
// LDS 32KB -> 5 blocks/CU (occupancy 30->~50%), same 2-buffer counted-vmcnt
// schedule. R21/R25 showed this kernel is occupancy-sensitive (latency-bound).
// qkv bf16, value fp8 e4m3.
// ---------------------------------------------------------------------------

typedef float f4 __attribute__((ext_vector_type(4)));
typedef float f32x4 __attribute__((ext_vector_type(4)));
typedef short s16x8 __attribute__((ext_vector_type(8)));
typedef unsigned short u16x4 __attribute__((ext_vector_type(4)));

__device__ __forceinline__ float wave_sum(float v) {
#pragma unroll
  for (int o = 32; o >= 1; o >>= 1) v += __shfl_xor(v, o, 64);
  return v;
}

__device__ __forceinline__ unsigned short f2bf(float f) {
  unsigned u = __float_as_uint(f);
  return (unsigned short)((u + 0x7fffu + ((u >> 16) & 1)) >> 16);
}

__device__ __forceinline__ unsigned char f2fp8(float f) {
  __hip_fp8_e4m3 v(f);
  return (unsigned char)v.__x;
}
__device__ __forceinline__ float fp82f(unsigned char b) {
  __hip_fp8_e4m3 v;
  v.__x = (__hip_fp8_storage_t)b;
  return (float)v;
}

// async 16B global -> LDS (per-lane gsrc, wave-linear LDS dst = base+lane*16)
__device__ __forceinline__ void gload_lds16(const void* g, void* l) {
  typedef const __attribute__((address_space(1))) unsigned int GU;
  typedef __attribute__((address_space(3))) unsigned int LU;
  __builtin_amdgcn_global_load_lds((GU*)(uintptr_t)g, (LU*)(uintptr_t)l, 16, 0, 0);
}

// ---------------------------------------------------------------------------
// Batched weight transpose + f32->bf16 (W[K][N] -> Wt[N][K], 32x32 tiles),
// with the val_w K-step-image reorder appended as a block tail.
struct TDesc { const float* src; unsigned short* dst; int K; int N; int tile0; };
struct TPack { TDesc d[12]; int rtile0; const float* rW; unsigned short* rB3; };

__launch_bounds__(256)
__global__ void transpose_cvt_kernel(TPack p)
{
  __shared__ float tl[32][33];
  int bid = blockIdx.x, tid = threadIdx.x;
  if (bid >= p.rtile0) {
    int idx = (bid - p.rtile0) * 256 + tid;
    int k = idx >> 8, n = idx & 255;
    p.rB3[((size_t)(k >> 5)) * 8192 + ((((k >> 3) & 3) * 256 + n) * 8) + (k & 7)] =
        f2bf(p.rW[idx]);
    return;
  }
  int e = 0;
#pragma unroll
  for (int i = 1; i < 12; ++i) if (bid >= p.d[i].tile0) e = i;
  const float* src = p.d[e].src;
  unsigned short* dst = p.d[e].dst;
  int K = p.d[e].K, N = p.d[e].N;
  int lt = bid - p.d[e].tile0;
  int tpr = N >> 5;
  int k0 = (lt / tpr) << 5, n0 = (lt % tpr) << 5;
  int r = tid >> 3, c4 = (tid & 7) << 2;
  f4 v = *(const f4*)(src + (size_t)(k0 + r) * N + n0 + c4);
#pragma unroll
  for (int j = 0; j < 4; ++j) tl[c4 + j][r] = v[j];
  __syncthreads();
  u16x4 o;
#pragma unroll
  for (int j = 0; j < 4; ++j) o[j] = f2bf(tl[r][c4 + j]);
  *(u16x4*)(dst + (size_t)(n0 + r) * K + k0 + c4) = o;
}

// ---------------------------------------------------------------------------
// Value projection: BM=64, BN=128, async gload_lds dbuf staging with counted
// vmcnt (4 loads/wave/step in flight). 32KB LDS -> 5 blocks/CU. Blocks are
// paired in N (bid&1) so A-rows are L2-shared. Output fp8 e4m3.
__launch_bounds__(256)
__global__ void gemm_val(const float* __restrict__ A, const unsigned short* __restrict__ B3,
                         const float* __restrict__ bias, unsigned char* __restrict__ C)
{
  constexpr int M = 199470, FM = 2, FN = 4;
  __shared__ __align__(16) float Af[2][8 * 64 * 4];   // 2 x 8 KB
  __shared__ __align__(16) s16x8 Bf[2][4 * 128];      // 2 x 8 KB
  int tid = threadIdx.x;
  int bid = blockIdx.x;
  int bm = (bid >> 1) * 64;
  int bn = (bid & 1) * 128;
  int lane = tid & 63, w = tid >> 6;
  int wr = w >> 1, wc = w & 1;
  int wm0 = wr * 32, wn0 = wc * 64;
  int p = lane >> 4, q = lane & 15;

  int arow = bm + lane;
  int arowc = arow < M ? arow : (M - 1);
  const float* ag0 = A + (size_t)arowc * 256 + (w * 2 + 0) * 4;
  const float* ag1 = A + (size_t)arowc * 256 + (w * 2 + 1) * 4;
  // B image: [ks][slice 4][n 256][elem 8]; wave w stages slice w, n in
  // [bn, bn+128) as two 1KB chunks.
  const unsigned short* bg = B3 + ((size_t)(w * 256 + bn) + lane) * 8;

  auto stage = [&](int buf, int ks) {
    gload_lds16(ag0 + ks * 32, &Af[buf][(w * 2 + 0) * 256]);
    gload_lds16(ag1 + ks * 32, &Af[buf][(w * 2 + 1) * 256]);
#pragma unroll
    for (int ui = 0; ui < 2; ++ui)
      gload_lds16(bg + (size_t)ks * 8192 + ui * 512, &Bf[buf][(w * 2 + ui) * 64]);
  };

  f32x4 acc[FM][FN] = {};
  stage(0, 0);
#pragma unroll 1
  for (int ks = 0; ks < 8; ++ks) {
    int cur = ks & 1;
    if (ks + 1 < 8) {
      stage(cur ^ 1, ks + 1);                          // 4 loads, stay in flight
      asm volatile("s_waitcnt vmcnt(4)" ::: "memory"); // stage(ks) landed
    } else {
      asm volatile("s_waitcnt vmcnt(0)" ::: "memory");
    }
    __builtin_amdgcn_s_barrier();
    s16x8 af[FM], bfr[FN];
#pragma unroll
    for (int i = 0; i < FM; ++i) {
      int row = wm0 + i * 16 + q;
      f4 x0 = *(const f4*)&Af[cur][(2 * p) * 256 + row * 4];
      f4 x1 = *(const f4*)&Af[cur][(2 * p + 1) * 256 + row * 4];
#pragma unroll
      for (int j = 0; j < 4; ++j) { af[i][j] = (short)f2bf(x0[j]); af[i][j + 4] = (short)f2bf(x1[j]); }
    }
#pragma unroll
    for (int j = 0; j < FN; ++j) bfr[j] = Bf[cur][p * 128 + wn0 + j * 16 + q];
#pragma unroll
    for (int i = 0; i < FM; ++i)
#pragma unroll
      for (int j = 0; j < FN; ++j)
        acc[i][j] = __builtin_amdgcn_mfma_f32_16x16x32_bf16(af[i], bfr[j], acc[i][j], 0, 0, 0);
    __builtin_amdgcn_s_barrier();
  }
  int p4 = p * 4;
#pragma unroll
  for (int i = 0; i < FM; ++i) {
#pragma unroll
    for (int rr = 0; rr < 4; ++rr) {
      int row = bm + wm0 + i * 16 + p4 + rr;
      if (row >= M) continue;
#pragma unroll
      for (int j = 0; j < FN; ++j) {
        int col = bn + wn0 + j * 16 + q;
        C[(size_t)row * 256 + col] = f2fp8(acc[i][j][rr] + bias[col]);
      }
    }
  }
}

// ---------------------------------------------------------------------------
// Grouped MFMA GEMM, BM=BN=64. mode: 0 none, 1 qp[row], 2 bcast.
// obf16: store output as bf16 (C cast to ushort*, ldc in elements).
struct GDesc {
  const float* A; const unsigned short* Wt; const float* bias; float* C;
  const float* qp;
  int M, K, ldc, nNb, mode, relu, obf16, block0;
};
struct GPack { GDesc d[4]; int n; };

__launch_bounds__(256)
__global__ void gemm_group(GPack g)
{
  constexpr int BM = 64, BN = 64, FM = 2, FN = 2;
  __shared__ __align__(16) s16x8 Als[2][4 * BM];
  __shared__ __align__(16) s16x8 Bls[2][4 * BN];
  int bid = blockIdx.x, tid = threadIdx.x;
  int e = 0;
#pragma unroll
  for (int i = 1; i < 4; ++i) if (i < g.n && bid >= g.d[i].block0) e = i;
  const GDesc& D = g.d[e];
  int M = D.M, K = D.K, nNb = D.nNb;
  int lb = bid - D.block0;
  int bm = (lb / nNb) * BM, bn = (lb % nNb) * BN;
  int lane = tid & 63, wid = tid >> 6;
  int wr = wid >> 1, wc = wid & 1;
  int wm0 = wr * 32, wn0 = wc * 32;
  int p = lane >> 4, q = lane & 15;
  int r = tid >> 2, qt = tid & 3;
  int bn8 = tid & 63, bks = tid >> 6;
  int arow = bm + r;
  bool rok = arow < M;
  const float* ap = D.A + (size_t)arow * K + qt * 8;
  const float* qpp = nullptr;
  if (D.mode == 1) qpp = D.qp + (size_t)arow * 256 + qt * 8;
  else if (D.mode == 2) qpp = D.qp + (size_t)((arow / 1500) * 300 + (arow % 300)) * 256 + qt * 8;
  const unsigned short* bp = D.Wt + (size_t)(bn + bn8) * K;

  f4 areg[2];
  s16x8 breg;
  auto loadA = [&](int k0) {
    f4 z = {0.f, 0.f, 0.f, 0.f};
    if (rok) {
      areg[0] = *(const f4*)(ap + k0);
      areg[1] = *(const f4*)(ap + k0 + 4);
      if (qpp) {
        areg[0] += *(const f4*)(qpp + k0);
        areg[1] += *(const f4*)(qpp + k0 + 4);
      }
    } else { areg[0] = z; areg[1] = z; }
  };
  auto loadB = [&](int k0) {
    breg = *(const s16x8*)(bp + k0 + bks * 8);
  };
  auto stage = [&](int buf) {
    s16x8 c0;
#pragma unroll
    for (int j = 0; j < 4; ++j) { c0[j] = (short)f2bf(areg[0][j]); c0[j + 4] = (short)f2bf(areg[1][j]); }
    Als[buf][qt * BM + r] = c0;
    Bls[buf][bks * BN + bn8] = breg;
  };

  f32x4 acc[FM][FN] = {};
  int nk = K >> 5;
  loadA(0); loadB(0); stage(0);
  __syncthreads();
  for (int ks = 0; ks < nk; ++ks) {
    int cur = ks & 1;
    bool more = (ks + 1) < nk;
    if (more) { loadA((ks + 1) << 5); loadB((ks + 1) << 5); }
    s16x8 af[FM], bfr[FN];
#pragma unroll
    for (int i = 0; i < FM; ++i) af[i] = Als[cur][p * BM + wm0 + i * 16 + q];
#pragma unroll
    for (int j = 0; j < FN; ++j) bfr[j] = Bls[cur][p * BN + wn0 + j * 16 + q];
#pragma unroll
    for (int i = 0; i < FM; ++i)
#pragma unroll
      for (int j = 0; j < FN; ++j)
        acc[i][j] = __builtin_amdgcn_mfma_f32_16x16x32_bf16(af[i], bfr[j], acc[i][j], 0, 0, 0);
    if (more) stage(cur ^ 1);
    __syncthreads();
  }
  int p4 = p * 4;
#pragma unroll
  for (int i = 0; i < FM; ++i) {
#pragma unroll
    for (int rr = 0; rr < 4; ++rr) {
      int row = bm + wm0 + i * 16 + p4 + rr;
      if (row >= M) continue;
#pragma unroll
      for (int j = 0; j < FN; ++j) {
        int col = bn + wn0 + j * 16 + q;
        float v = acc[i][j][rr] + D.bias[col];
        if (D.relu) v = fmaxf(v, 0.0f);
        if (D.obf16)
          ((unsigned short*)D.C)[(size_t)row * D.ldc + col] = f2bf(v);
        else
          D.C[(size_t)row * D.ldc + col] = v;
      }
    }
  }
}

// ---------------------------------------------------------------------------
__launch_bounds__(256)
__global__ void add_ln_kernel(const float* __restrict__ a, const float* __restrict__ b,
                              const float* __restrict__ g, const float* __restrict__ be,
                              float* __restrict__ out)
{
  __shared__ float red[4];
  int row = blockIdx.x, c = threadIdx.x;
  size_t i = (size_t)row * 256 + c;
  float x = a[i] + b[i];
  float w = wave_sum(x);
  int wid = c >> 6;
  if ((c & 63) == 0) red[wid] = w;
  __syncthreads();
  float mean = (red[0] + red[1] + red[2] + red[3]) * (1.0f / 256.0f);
  float d = x - mean;
  __syncthreads();
  w = wave_sum(d * d);
  if ((c & 63) == 0) red[wid] = w;
  __syncthreads();
  float var = (red[0] + red[1] + red[2] + red[3]) * (1.0f / 256.0f);
  out[i] = d * rsqrtf(var + 1e-5f) * g[c] + be[c];
}

__launch_bounds__(256)
__global__ void add_ln2_kernel(const float* a0, const float* b0, const float* g0,
                               const float* be0, float* o0,
                               const float* a1, const float* b1, const float* g1,
                               const float* be1, float* o1, int m0)
{
  __shared__ float red[4];
  int row = blockIdx.x, c = threadIdx.x;
  const float *a, *b, *g, *be; float* out;
  if (row < m0) { a = a0; b = b0; g = g0; be = be0; out = o0; }
  else { row -= m0; a = a1; b = b1; g = g1; be = be1; out = o1; }
  size_t i = (size_t)row * 256 + c;
  float x = a[i] + b[i];
  float w = wave_sum(x);
  int wid = c >> 6;
  if ((c & 63) == 0) red[wid] = w;
  __syncthreads();
  float mean = (red[0] + red[1] + red[2] + red[3]) * (1.0f / 256.0f);
  float d = x - mean;
  __syncthreads();
  w = wave_sum(d * d);
  if ((c & 63) == 0) red[wid] = w;
  __syncthreads();
  float var = (red[0] + red[1] + red[2] + red[3]) * (1.0f / 256.0f);
  out[i] = d * rsqrtf(var + 1e-5f) * g[c] + be[c];
}

__launch_bounds__(256)
__global__ void add_ln_tw_kernel(const float* __restrict__ a, const float* __restrict__ b,
                                 const float* __restrict__ g, const float* __restrict__ be,
                                 const float* __restrict__ tw_w, const float* __restrict__ tw_b,
                                 float* __restrict__ out, float* __restrict__ tw_raw)
{
  __shared__ float red[4];
  int row = blockIdx.x, c = threadIdx.x;
  size_t i = (size_t)row * 256 + c;
  float x = a[i] + b[i];
  float w = wave_sum(x);
  int wid = c >> 6;
  if ((c & 63) == 0) red[wid] = w;
  __syncthreads();
  float mean = (red[0] + red[1] + red[2] + red[3]) * (1.0f / 256.0f);
  float d = x - mean;
  __syncthreads();
  w = wave_sum(d * d);
  if ((c & 63) == 0) red[wid] = w;
  __syncthreads();
  float var = (red[0] + red[1] + red[2] + red[3]) * (1.0f / 256.0f);
  float v = d * rsqrtf(var + 1e-5f) * g[c] + be[c];
  out[i] = v;
  __syncthreads();
  float tws = wave_sum(v * tw_w[c]);
  if ((c & 63) == 0) red[wid] = tws;
  __syncthreads();
  if (c == 0) tw_raw[row] = red[0] + red[1] + red[2] + red[3] + tw_b[0];
}

__launch_bounds__(256)
__global__ void tw_ln_kernel(const float* __restrict__ tw_raw, const float* __restrict__ t2c,
                             const float* __restrict__ cls_s, const float* __restrict__ g,
                             const float* __restrict__ be, float* __restrict__ out)
{
  __shared__ float red[4];
  int nq = blockIdx.x;
  int n = nq / 300, q = nq % 300;
  int c = threadIdx.x;
  float s[5], m = -1e30f;
#pragma unroll
  for (int f = 0; f < 5; ++f) { s[f] = tw_raw[(n * 5 + f) * 300 + q]; m = fmaxf(m, s[f]); }
  float sum = 0.f;
#pragma unroll
  for (int f = 0; f < 5; ++f) { s[f] = __expf(s[f] - m); sum += s[f]; }
  float inv = 1.0f / sum;
  float acc = 0.f;
#pragma unroll
  for (int f = 0; f < 5; ++f)
    acc += t2c[((size_t)(n * 5 + f) * 300 + q) * 256 + c] * s[f];
  float x = cls_s[(size_t)nq * 256 + c] + acc * inv;
  float w = wave_sum(x);
  int wid = c >> 6;
  if ((c & 63) == 0) red[wid] = w;
  __syncthreads();
  float mean = (red[0] + red[1] + red[2] + red[3]) * (1.0f / 256.0f);
  float d = x - mean;
  __syncthreads();
  w = wave_sum(d * d);
  if ((c & 63) == 0) red[wid] = w;
  __syncthreads();
  float var = (red[0] + red[1] + red[2] + red[3]) * (1.0f / 256.0f);
  out[(size_t)nq * 256 + c] = d * rsqrtf(var + 1e-5f) * g[c] + be[c];
}

// ---------------------------------------------------------------------------
// MFMA MHA; qkv is bf16 (written directly by the QKV GEMM). Q-scale folded
// into the f32 scores. Blocks 0..79 cls, 80..479 loc.
__launch_bounds__(256)
__global__ void attn_mfma_kernel(const unsigned short* __restrict__ qkv_c, float* __restrict__ out_c,
                                 const unsigned short* __restrict__ qkv_l, float* __restrict__ out_l)
{
  constexpr int L = 300, NKT = 19;
  __shared__ __align__(16) short Kf[NKT * 64 * 8];
  __shared__ __align__(16) short Vf[10 * 2 * 64 * 8];
  __shared__ __align__(16) short Pf[4][5 * 64 * 8];
  int bid = blockIdx.x;
  const unsigned short* qkv; float* out; int sub;
  if (bid < 80) { qkv = qkv_c; out = out_c; sub = bid; }
  else { qkv = qkv_l; out = out_l; sub = bid - 80; }
  int b = sub / 40;
  int h = (sub % 40) / 5;
  int band = sub % 5;
  int tid = threadIdx.x;
  int lane = tid & 63, w = tid >> 6;
  int c = lane & 15, sl = lane >> 4, jj = lane & 7;
  const unsigned short* base = qkv + (size_t)b * L * 768;

  {
    s16x8 z = {};
    for (int i = tid; i < 10 * 2 * 64; i += 256) *(s16x8*)&Vf[i * 8] = z;
  }
  // K staging: raw 16B copies (bf16 source), frag layout as before.
  for (int idx = tid; idx < 1200; idx += 256) {
    int key = idx >> 2, s = idx & 3;
    s16x8 kv = *(const s16x8*)(base + (size_t)key * 768 + 256 + h * 32 + s * 8);
    *(s16x8*)&Kf[(((key >> 4) * 64) + ((s << 4) | (key & 15))) * 8] = kv;
  }
  __syncthreads();  // V zero-fill visible before scatter
  for (int idx = tid; idx < 1200; idx += 256) {
    int key = idx >> 2, s = idx & 3;
    s16x8 vv = *(const s16x8*)(base + (size_t)key * 768 + 512 + h * 32 + s * 8);
    int bb = (((key >> 5) * 2 + (s >> 1)) * 64) * 8;
    int lane0 = (((key >> 3) & 3) << 4) | ((s & 1) * 8);
    int elem = key & 7;
#pragma unroll
    for (int j = 0; j < 8; ++j)
      Vf[bb + (lane0 + j) * 8 + elem] = vv[j];
  }
  int qloc = band * 64 + w * 16 + c;
  int qr = qloc < L ? qloc : L - 1;
  s16x8 qfrag = *(const s16x8*)(base + (size_t)qr * 768 + h * 32 + sl * 8);
  __syncthreads();

  f32x4 sc[NKT];
#pragma unroll
  for (int kt = 0; kt < NKT; ++kt) {
    s16x8 kfr = *(const s16x8*)&Kf[(kt * 64 + lane) * 8];
    f32x4 z = {};
    sc[kt] = __builtin_amdgcn_mfma_f32_16x16x32_bf16(qfrag, kfr, z, 0, 0, 0);
  }
  constexpr float kscale = 0.17677669529663687f;   // 1/sqrt(32), folded from Q
#pragma unroll
  for (int kt = 0; kt < NKT; ++kt)
#pragma unroll
    for (int r = 0; r < 4; ++r) sc[kt][r] *= kscale;
  if (c >= 12) {
#pragma unroll
    for (int r = 0; r < 4; ++r) sc[18][r] = -1e30f;
  }

  float inv[4];
#pragma unroll
  for (int r = 0; r < 4; ++r) {
    float m = sc[0][r];
#pragma unroll
    for (int kt = 1; kt < NKT; ++kt) m = fmaxf(m, sc[kt][r]);
#pragma unroll
    for (int o = 1; o < 16; o <<= 1) m = fmaxf(m, __shfl_xor(m, o, 64));
    float s = 0.f;
#pragma unroll
    for (int kt = 0; kt < NKT; ++kt) { float e = __expf(sc[kt][r] - m); sc[kt][r] = e; s += e; }
#pragma unroll
    for (int o = 1; o < 16; o <<= 1) s += __shfl_xor(s, o, 64);
    inv[r] = 1.0f / s;
  }

  f32x4 oacc[2] = {};
  short* Pw = &Pf[w][0];
#pragma unroll
  for (int ch = 0; ch < 2; ++ch) {
    int kt0 = ch * 10, kt1 = (ch == 0) ? 10 : NKT;
#pragma unroll
    for (int kt = kt0; kt < kt1; ++kt) {
      int t = (kt >> 1) - ch * 5;
      int slice = ((kt & 1) << 1) | (c >> 3);
#pragma unroll
      for (int r = 0; r < 4; ++r) {
        int qrow = sl * 4 + r;
        Pw[(t * 64 + (slice << 4) + qrow) * 8 + jj] = (short)f2bf(sc[kt][r] * inv[r]);
      }
    }
#pragma unroll
    for (int t = 0; t < 5; ++t) {
      s16x8 pfr = *(const s16x8*)&Pw[(t * 64 + lane) * 8];
#pragma unroll
      for (int dh = 0; dh < 2; ++dh) {
        s16x8 vfr = *(const s16x8*)&Vf[((((ch * 5 + t) * 2) + dh) * 64 + lane) * 8];
        oacc[dh] = __builtin_amdgcn_mfma_f32_16x16x32_bf16(pfr, vfr, oacc[dh], 0, 0, 0);
      }
    }
  }

#pragma unroll
  for (int r = 0; r < 4; ++r) {
    int qo = band * 64 + w * 16 + sl * 4 + r;
    if (qo < L) {
#pragma unroll
      for (int dh = 0; dh < 2; ++dh)
        out[((size_t)(b * L + qo)) * 256 + h * 32 + dh * 16 + c] = oacc[dh][r];
    }
  }
}

// ---------------------------------------------------------------------------
// MSDA bilinear sampling with folded per-head softmax; value is fp8 e4m3.
__launch_bounds__(256)
__global__ void msda_kernel(const float* __restrict__ offp, const float* __restrict__ awp,
                            const float* __restrict__ refp,
                            const unsigned char* __restrict__ value,
                            float* __restrict__ out)
{
  const int Hs[4] = {100, 50, 25, 13};
  const int Ws[4] = {150, 75, 38, 19};
  const int st[4] = {0, 15000, 18750, 19700};
  __shared__ float saw[128];
  int row = blockIdx.x;
  int b = row / 300;
  int tid = threadIdx.x;
  if (tid < 128) {
    float v = awp[(size_t)row * 128 + tid];
    float m = v;
#pragma unroll
    for (int o = 1; o < 16; o <<= 1) m = fmaxf(m, __shfl_xor(m, o, 16));
    float e = __expf(v - m);
    float s = e;
#pragma unroll
    for (int o = 1; o < 16; o <<= 1) s += __shfl_xor(s, o, 16);
    saw[tid] = e / s;
  }
  __syncthreads();
  int h = tid >> 5, d2 = tid & 31;
  const float* offr = offp + (size_t)row * 256 + h * 32;
  const float* awr = saw + h * 16;
  const float* rf = refp + (size_t)row * 8;
  const unsigned char* vb = value + (size_t)b * 19947 * 256;
  float acc = 0.f;
#pragma unroll
  for (int l = 0; l < 4; ++l) {
    int H = Hs[l], W = Ws[l];
    float rx = rf[l * 2 + 0], ry = rf[l * 2 + 1];
#pragma unroll
    for (int pp = 0; pp < 4; ++pp) {
      float ox = offr[l * 8 + pp * 2 + 0], oy = offr[l * 8 + pp * 2 + 1];
      float x = (rx + ox / (float)W) * (float)W - 0.5f;
      float y = (ry + oy / (float)H) * (float)H - 0.5f;
      float x0f = floorf(x), y0f = floorf(y);
      float wx = x - x0f, wy = y - y0f;
      int x0 = (int)x0f, y0 = (int)y0f;
      float aw = awr[l * 4 + pp];
      float sv = 0.f;
#pragma unroll
      for (int cy = 0; cy < 2; ++cy) {
#pragma unroll
        for (int cx = 0; cx < 2; ++cx) {
          int ix = x0 + cx, iy = y0 + cy;
          bool valid = (ix >= 0) && (ix < W) && (iy >= 0) && (iy < H);
          float gg = 0.f;
          if (valid) {
            int idx = iy * W + ix;
            gg = fp82f(vb[((size_t)(st[l] + idx)) * 256 + h * 32 + d2]);
          }
          float wgt = (cx ? wx : 1.f - wx) * (cy ? wy : 1.f - wy);
          sv += gg * wgt;
        }
      }
      acc += sv * aw;
    }
  }
  out[(size_t)row * 256 + tid] = acc;
}

// ---------------------------------------------------------------------------
struct GArg { const float* A; const unsigned short* Wt; const float* bias; float* C;
              const float* qp; int M, N, K, ldc, mode, relu, obf16; };

static void launch_group(hipStream_t st, const GArg* a, int n)
{
  GPack g; g.n = n;
  int blocks = 0;
  for (int i = 0; i < n; ++i) {
    GDesc& d = g.d[i];
    d.A = a[i].A; d.Wt = a[i].Wt; d.bias = a[i].bias; d.C = a[i].C; d.qp = a[i].qp;
    d.M = a[i].M; d.K = a[i].K; d.ldc = a[i].ldc; d.nNb = a[i].N / 64;
    d.mode = a[i].mode; d.relu = a[i].relu; d.obf16 = a[i].obf16; d.block0 = blocks;
    blocks += ((a[i].M + 63) / 64) * d.nNb;
  }
  for (int i = n; i < 4; ++i) g.d[i] = g.d[n - 1];
  gemm_group<<<blocks, 256, 0, st>>>(g);
}

extern "C" void kernel_launch(void* const* d_in, const int* in_sizes, int n_in,
                              void* d_out, int out_size, void* d_ws, size_t ws_size,
                              hipStream_t stream)
{
  const float* tgt_cls   = (const float*)d_in[0];
  const float* tgt_loc   = (const float*)d_in[1];
  const float* query_pos = (const float*)d_in[2];
  const float* refp      = (const float*)d_in[3];
  const float* src       = (const float*)d_in[4];
  const float* in_w_cls = (const float*)d_in[8];
  const float* in_b_cls = (const float*)d_in[9];
  const float* out_w_cls = (const float*)d_in[10];
  const float* out_b_cls = (const float*)d_in[11];
  const float* in_w_loc = (const float*)d_in[12];
  const float* in_b_loc = (const float*)d_in[13];
  const float* out_w_loc = (const float*)d_in[14];
  const float* out_b_loc = (const float*)d_in[15];
  const float* off_w = (const float*)d_in[16];
  const float* off_b = (const float*)d_in[17];
  const float* aw_w = (const float*)d_in[18];
  const float* aw_b = (const float*)d_in[19];
  const float* val_w = (const float*)d_in[20];
  const float* val_b = (const float*)d_in[21];
  const float* cow = (const float*)d_in[22];
  const float* cob = (const float*)d_in[23];
  const float* l1w_cls = (const float*)d_in[24];
  const float* l1b_cls = (const float*)d_in[25];
  const float* l2w_cls = (const float*)d_in[26];
  const float* l2b_cls = (const float*)d_in[27];
  const float* l1w_loc = (const float*)d_in[28];
  const float* l1b_loc = (const float*)d_in[29];
  const float* l2w_loc = (const float*)d_in[30];
  const float* l2b_loc = (const float*)d_in[31];
  const float* n1c_g = (const float*)d_in[32]; const float* n1c_b = (const float*)d_in[33];
  const float* n1l_g = (const float*)d_in[34]; const float* n1l_b = (const float*)d_in[35];
  const float* n2c_g = (const float*)d_in[36]; const float* n2c_b = (const float*)d_in[37];
  const float* n2l_g = (const float*)d_in[38]; const float* n2l_b = (const float*)d_in[39];
  const float* n3c_g = (const float*)d_in[40]; const float* n3c_b = (const float*)d_in[41];
  const float* n3l_g = (const float*)d_in[42]; const float* n3l_b = (const float*)d_in[43];
  const float* tw_w = (const float*)d_in[44];  const float* tw_b = (const float*)d_in[45];

  float* out_cls = (float*)d_out;            // (2,300,256)
  float* out_loc = (float*)d_out + 153600;   // (2,5,300,256)

  char* w = (char*)d_ws;
  size_t o = 0;
  auto F = [&](size_t n) -> float* {
    float* p = (float*)(w + o);
    o += ((n * 4 + 255) & ~(size_t)255);
    return p;
  };
  auto B16 = [&](size_t n) -> unsigned short* {
    unsigned short* p = (unsigned short*)(w + o);
    o += ((n * 2 + 255) & ~(size_t)255);
    return p;
  };
  auto B8 = [&](size_t n) -> unsigned char* {
    unsigned char* p = (unsigned char*)(w + o);
    o += ((n + 255) & ~(size_t)255);
    return p;
  };
  unsigned short* qkv_c = B16(600 * 768);    // bf16 QKV
  float* attno_c = F(600 * 256);
  float* t2_c    = F(600 * 256);
  float* cls_s   = F(600 * 256);
  float* cls_mid = F(600 * 256);
  float* hc1     = F(600 * 1024);
  float* hc2     = F(600 * 256);
  unsigned short* qkv_l = B16(3000 * 768);   // bf16 QKV
  float* attno_l = F(3000 * 256);
  float* t2l     = F(3000 * 256);
  float* loc_s   = F(3000 * 256);
  float* offp    = F(3000 * 256);
  float* awp     = F(3000 * 128);
  float* samp    = F(3000 * 256);
  float* t2c     = F(3000 * 256);
  float* loc_o   = F(3000 * 256);
  float* h1      = F(3000 * 1024);
  float* h2      = F(3000 * 256);
  float* tw_raw  = F(3000);
  unsigned char* value = B8((size_t)199470 * 256);   // fp8 e4m3
  unsigned short* wt_in_cls  = B16(768 * 256);
  unsigned short* wt_in_loc  = B16(768 * 256);
  unsigned short* wt_out_cls = B16(256 * 256);
  unsigned short* wt_out_loc = B16(256 * 256);
  unsigned short* wt_off     = B16(256 * 256);
  unsigned short* wt_aw      = B16(128 * 256);
  unsigned short* wv3        = B16(256 * 256);   // K-step LDS-image layout
  unsigned short* wt_cow     = B16(256 * 256);
  unsigned short* wt_l1_cls  = B16(1024 * 256);
  unsigned short* wt_l2_cls  = B16(256 * 1024);
  unsigned short* wt_l1_loc  = B16(1024 * 256);
  unsigned short* wt_l2_loc  = B16(256 * 1024);

  // ---- 1. Weight transpose+convert (+val_w reorder tail) ----
  TPack tp;
  auto TE = [](const float* s, unsigned short* d, int K, int N) { TDesc t; t.src = s; t.dst = d; t.K = K; t.N = N; t.tile0 = 0; return t; };
  tp.d[0]  = TE(in_w_cls, wt_in_cls, 256, 768);
  tp.d[1]  = TE(in_w_loc, wt_in_loc, 256, 768);
  tp.d[2]  = TE(out_w_cls, wt_out_cls, 256, 256);
  tp.d[3]  = TE(out_w_loc, wt_out_loc, 256, 256);
  tp.d[4]  = TE(off_w, wt_off, 256, 256);
  tp.d[5]  = TE(aw_w, wt_aw, 256, 128);
  tp.d[6]  = TE(cow, wt_cow, 256, 256);
  tp.d[7]  = TE(l1w_cls, wt_l1_cls, 256, 1024);
  tp.d[8]  = TE(l2w_cls, wt_l2_cls, 1024, 256);
  tp.d[9]  = TE(l1w_loc, wt_l1_loc, 256, 1024);
  tp.d[10] = TE(l2w_loc, wt_l2_loc, 1024, 256);
  tp.d[11] = TE(l2w_loc, wt_l2_loc, 1024, 256);  // dummy (never selected first)
  int tiles = 0;
  for (int i = 0; i < 11; ++i) { tp.d[i].tile0 = tiles; tiles += (tp.d[i].K >> 5) * (tp.d[i].N >> 5); }
  tp.d[11].tile0 = tiles - (tp.d[10].K >> 5) * (tp.d[10].N >> 5);
  tp.rtile0 = tiles; tp.rW = val_w; tp.rB3 = wv3;
  transpose_cvt_kernel<<<tiles + 256, 256, 0, stream>>>(tp);

  // ---- 2. Value projection (dominant; launch early) ----
  gemm_val<<<((199470 + 63) / 64) * 2, 256, 0, stream>>>(src, wv3, val_b, value);

  // ---- 3. QKV projections for cls+loc (adds folded in; bf16 out) ----
  {
    GArg a[4] = {
      {tgt_cls, wt_in_cls,             in_b_cls,       (float*)qkv_c,         query_pos, 600, 512, 256, 768, 1, 0, 1},
      {tgt_cls, wt_in_cls + 512 * 256, in_b_cls + 512, (float*)(qkv_c + 512), nullptr,   600, 256, 256, 768, 0, 0, 1},
      {tgt_loc, wt_in_loc,             in_b_loc,       (float*)qkv_l,         query_pos, 3000, 512, 256, 768, 2, 0, 1},
      {tgt_loc, wt_in_loc + 512 * 256, in_b_loc + 512, (float*)(qkv_l + 512), nullptr,   3000, 256, 256, 768, 0, 0, 1},
    };
    launch_group(stream, a, 4);
  }
  // ---- 4. Both self-attentions ----
  attn_mfma_kernel<<<480, 256, 0, stream>>>(qkv_c, attno_c, qkv_l, attno_l);
  // ---- 5. Output projections ----
  {
    GArg a[2] = {
      {attno_c, wt_out_cls, out_b_cls, t2_c, nullptr, 600, 256, 256, 256, 0, 0, 0},
      {attno_l, wt_out_loc, out_b_loc, t2l,  nullptr, 3000, 256, 256, 256, 0, 0, 0},
    };
    launch_group(stream, a, 2);
  }
  // ---- 6. Post-attention LayerNorms ----
  add_ln2_kernel<<<3600, 256, 0, stream>>>(tgt_cls, t2_c, n2c_g, n2c_b, cls_s,
                                           tgt_loc, t2l, n2l_g, n2l_b, loc_s, 600);
  // ---- 7. Offset + attention-weight projections (query add folded) ----
  {
    GArg a[2] = {
      {loc_s, wt_off, off_b, offp, query_pos, 3000, 256, 256, 256, 2, 0, 0},
      {loc_s, wt_aw,  aw_b,  awp,  query_pos, 3000, 128, 256, 128, 2, 0, 0},
    };
    launch_group(stream, a, 2);
  }
  // ---- 8. MSDA sampling ----
  msda_kernel<<<3000, 256, 0, stream>>>(offp, awp, refp, value, samp);
  // ---- 9. Cross output projection ----
  {
    GArg a[1] = {{samp, wt_cow, cob, t2c, nullptr, 3000, 256, 256, 256, 0, 0, 0}};
    launch_group(stream, a, 1);
  }
  // ---- 10. LN (n1l) ----
  add_ln_kernel<<<3000, 256, 0, stream>>>(loc_s, t2c, n1l_g, n1l_b, loc_o);
  // ---- 11-12. loc FFN ----
  {
    GArg a[1] = {{loc_o, wt_l1_loc, l1b_loc, h1, nullptr, 3000, 1024, 256, 1024, 0, 1, 0}};
    launch_group(stream, a, 1);
  }
  {
    GArg a[1] = {{h1, wt_l2_loc, l2b_loc, h2, nullptr, 3000, 256, 1024, 256, 0, 0, 0}};
    launch_group(stream, a, 1);
  }
  // ---- 13. LN (n3l) -> out_loc, fused temporal dot ----
  add_ln_tw_kernel<<<3000, 256, 0, stream>>>(loc_o, h2, n3l_g, n3l_b, tw_w, tw_b,
                                             out_loc, tw_raw);
  // ---- 14. temporal softmax+combine + LN (n1c) -> cls_mid ----
  tw_ln_kernel<<<600, 256, 0, stream>>>(tw_raw, t2c, cls_s, n1c_g, n1c_b, cls_mid);
  // ---- 15-16. cls FFN ----
  {
    GArg a[1] = {{cls_mid, wt_l1_cls, l1b_cls, hc1, nullptr, 600, 1024, 256, 1024, 0, 1, 0}};
    launch_group(stream, a, 1);
  }
  {
    GArg a[1] = {{hc1, wt_l2_cls, l2b_cls, hc2, nullptr, 600, 256, 1024, 256, 0, 0, 0}};
    launch_group(stream, a, 1);
  }
  // ---- 17. LN (n3c) -> out_cls ----
  add_ln_kernel<<<600, 256, 0, stream>>>(cls_mid, hc2, n3c_g, n3c_b, out_cls);
}

// Round 27
// 324.215 us; speedup vs baseline: 1.1530x; 1.1530x over previous
//
#include <hip/hip_runtime.h>
#include <hip/hip_bf16.h>
#include <hip/hip_fp8.h>
#include <stdint.h>

// ---------------------------------------------------------------------------
// DeformableTransformerDecoderLayer: N=2, nf=5, Q=300, C=256, NH=8, d=32,
// NL=4, NP=4, DFF=1024. Levels (H,W): (100,150),(50,75),(25,38),(13,19),
// starts {0,15000,18750,19700}, LIN=19947.
// R24 build (335.9us best) with gemm_val A-path reg-staged: A loads
// global->reg during stage, converted to bf16 ONCE, ds_written in MFMA-frag
// layout (T14 issue-early/write-late). Hot loop = pure ds_read+MFMA.
// LDS 48->40KB (4 blocks/CU). B keeps async gload_lds + counted vmcnt.
// qkv bf16, value fp8 e4m3.
// ---------------------------------------------------------------------------

typedef float f4 __attribute__((ext_vector_type(4)));
typedef float f32x4 __attribute__((ext_vector_type(4)));
typedef short s16x8 __attribute__((ext_vector_type(8)));
typedef unsigned short u16x4 __attribute__((ext_vector_type(4)));

__device__ __forceinline__ float wave_sum(float v) {
#pragma unroll
  for (int o = 32; o >= 1; o >>= 1) v += __shfl_xor(v, o, 64);
  return v;
}

__device__ __forceinline__ unsigned short f2bf(float f) {
  unsigned u = __float_as_uint(f);
  return (unsigned short)((u + 0x7fffu + ((u >> 16) & 1)) >> 16);
}

__device__ __forceinline__ unsigned char f2fp8(float f) {
  __hip_fp8_e4m3 v(f);
  return (unsigned char)v.__x;
}
__device__ __forceinline__ float fp82f(unsigned char b) {
  __hip_fp8_e4m3 v;
  v.__x = (__hip_fp8_storage_t)b;
  return (float)v;
}

// async 16B global -> LDS (per-lane gsrc, wave-linear LDS dst = base+lane*16)
__device__ __forceinline__ void gload_lds16(const void* g, void* l) {
  typedef const __attribute__((address_space(1))) unsigned int GU;
  typedef __attribute__((address_space(3))) unsigned int LU;
  __builtin_amdgcn_global_load_lds((GU*)(uintptr_t)g, (LU*)(uintptr_t)l, 16, 0, 0);
}

// ---------------------------------------------------------------------------
// Batched weight transpose + f32->bf16 (W[K][N] -> Wt[N][K], 32x32 tiles),
// with the val_w K-step-image reorder appended as a block tail.
struct TDesc { const float* src; unsigned short* dst; int K; int N; int tile0; };
struct TPack { TDesc d[12]; int rtile0; const float* rW; unsigned short* rB3; };

__launch_bounds__(256)
__global__ void transpose_cvt_kernel(TPack p)
{
  __shared__ float tl[32][33];
  int bid = blockIdx.x, tid = threadIdx.x;
  if (bid >= p.rtile0) {
    int idx = (bid - p.rtile0) * 256 + tid;
    int k = idx >> 8, n = idx & 255;
    p.rB3[((size_t)(k >> 5)) * 8192 + ((((k >> 3) & 3) * 256 + n) * 8) + (k & 7)] =
        f2bf(p.rW[idx]);
    return;
  }
  int e = 0;
#pragma unroll
  for (int i = 1; i < 12; ++i) if (bid >= p.d[i].tile0) e = i;
  const float* src = p.d[e].src;
  unsigned short* dst = p.d[e].dst;
  int K = p.d[e].K, N = p.d[e].N;
  int lt = bid - p.d[e].tile0;
  int tpr = N >> 5;
  int k0 = (lt / tpr) << 5, n0 = (lt % tpr) << 5;
  int r = tid >> 3, c4 = (tid & 7) << 2;
  f4 v = *(const f4*)(src + (size_t)(k0 + r) * N + n0 + c4);
#pragma unroll
  for (int j = 0; j < 4; ++j) tl[c4 + j][r] = v[j];
  __syncthreads();
  u16x4 o;
#pragma unroll
  for (int j = 0; j < 4; ++j) o[j] = f2bf(tl[r][c4 + j]);
  *(u16x4*)(dst + (size_t)(n0 + r) * K + k0 + c4) = o;
}

// ---------------------------------------------------------------------------
// Value projection: BM=64, BN=256. A reg-staged (global->reg->cvt->ds_write,
// frag layout); B async gload_lds. 2-buffer counted-vmcnt schedule:
//   iter: issue A(k+1)->reg + B(k+1)->LDS [6 vm] ; vmcnt(6) [B(k) landed] ;
//         barrier ; compute(k) ; vmcnt(4) [A(k+1) regs] ; writeA(k+1) ; barrier
// LDS 40KB -> 4 blocks/CU. Output fp8 e4m3.
__launch_bounds__(256)
__global__ void gemm_val(const float* __restrict__ A, const unsigned short* __restrict__ B3,
                         const float* __restrict__ bias, unsigned char* __restrict__ C)
{
  constexpr int M = 199470, FM = 2, FN = 8;
  __shared__ __align__(16) s16x8 Als[2][4 * 64];      // 2 x 4 KB (bf16 frag layout)
  __shared__ __align__(16) s16x8 Bf[2][4 * 256];      // 2 x 16 KB
  int tid = threadIdx.x;
  int bm = blockIdx.x * 64;
  int lane = tid & 63, w = tid >> 6;
  int wr = w >> 1, wc = w & 1;
  int wm0 = wr * 32, wn0 = wc * 128;
  int p = lane >> 4, q = lane & 15;

  // A reg-staging: thread t -> row r=t>>2, k-slice qt=t&3 (8 floats each)
  int r = tid >> 2, qt = tid & 3;
  int arow = bm + r;
  int arowc = arow < M ? arow : (M - 1);
  const float* ap = A + (size_t)arowc * 256 + qt * 8;
  const unsigned short* bg = B3 + ((size_t)(w * 4) * 64 + lane) * 8;

  f4 areg0, areg1;
  auto loadA = [&](int k0) {
    areg0 = *(const f4*)(ap + k0);
    areg1 = *(const f4*)(ap + k0 + 4);
  };
  auto stageB = [&](int buf, int ks) {
#pragma unroll
    for (int ui = 0; ui < 4; ++ui)
      gload_lds16(bg + (size_t)ks * 8192 + ui * 512, &Bf[buf][(w * 4 + ui) * 64]);
  };
  auto writeA = [&](int buf) {
    s16x8 c0;
#pragma unroll
    for (int j = 0; j < 4; ++j) { c0[j] = (short)f2bf(areg0[j]); c0[j + 4] = (short)f2bf(areg1[j]); }
    Als[buf][qt * 64 + r] = c0;
  };

  f32x4 acc[FM][FN] = {};
  loadA(0);                                           // 2 vm
  stageB(0, 0);                                       // 4 vm
  asm volatile("s_waitcnt vmcnt(4)" ::: "memory");    // A(0) regs arrived
  writeA(0);
#pragma unroll 1
  for (int ks = 0; ks < 8; ++ks) {
    int cur = ks & 1;
    bool more = (ks + 1) < 8;
    if (more) {
      loadA((ks + 1) << 5);                           // 2 vm -> aregs
      stageB(cur ^ 1, ks + 1);                        // 4 vm -> Bf[nxt]
      asm volatile("s_waitcnt vmcnt(6)" ::: "memory"); // B(ks) landed in LDS
    } else {
      asm volatile("s_waitcnt vmcnt(0)" ::: "memory");
    }
    __builtin_amdgcn_s_barrier();                     // Als[cur], Bf[cur] visible
    s16x8 af[FM], bfr[FN];
#pragma unroll
    for (int i = 0; i < FM; ++i) af[i] = Als[cur][p * 64 + wm0 + i * 16 + q];
#pragma unroll
    for (int j = 0; j < FN; ++j) bfr[j] = Bf[cur][p * 256 + wn0 + j * 16 + q];
#pragma unroll
    for (int i = 0; i < FM; ++i)
#pragma unroll
      for (int j = 0; j < FN; ++j)
        acc[i][j] = __builtin_amdgcn_mfma_f32_16x16x32_bf16(af[i], bfr[j], acc[i][j], 0, 0, 0);
    if (more) {
      asm volatile("s_waitcnt vmcnt(4)" ::: "memory"); // A(ks+1) regs arrived
      writeA(cur ^ 1);                                // ds_write Als[nxt]
    }
    __builtin_amdgcn_s_barrier();
  }
  int p4 = p * 4;
#pragma unroll
  for (int i = 0; i < FM; ++i) {
#pragma unroll
    for (int rr = 0; rr < 4; ++rr) {
      int row = bm + wm0 + i * 16 + p4 + rr;
      if (row >= M) continue;
#pragma unroll
      for (int j = 0; j < FN; ++j) {
        int col = wn0 + j * 16 + q;
        C[(size_t)row * 256 + col] = f2fp8(acc[i][j][rr] + bias[col]);
      }
    }
  }
}

// ---------------------------------------------------------------------------
// Grouped MFMA GEMM, BM=BN=64. mode: 0 none, 1 qp[row], 2 bcast.
// obf16: store output as bf16 (C cast to ushort*, ldc in elements).
struct GDesc {
  const float* A; const unsigned short* Wt; const float* bias; float* C;
  const float* qp;
  int M, K, ldc, nNb, mode, relu, obf16, block0;
};
struct GPack { GDesc d[4]; int n; };

__launch_bounds__(256)
__global__ void gemm_group(GPack g)
{
  constexpr int BM = 64, BN = 64, FM = 2, FN = 2;
  __shared__ __align__(16) s16x8 Als[2][4 * BM];
  __shared__ __align__(16) s16x8 Bls[2][4 * BN];
  int bid = blockIdx.x, tid = threadIdx.x;
  int e = 0;
#pragma unroll
  for (int i = 1; i < 4; ++i) if (i < g.n && bid >= g.d[i].block0) e = i;
  const GDesc& D = g.d[e];
  int M = D.M, K = D.K, nNb = D.nNb;
  int lb = bid - D.block0;
  int bm = (lb / nNb) * BM, bn = (lb % nNb) * BN;
  int lane = tid & 63, wid = tid >> 6;
  int wr = wid >> 1, wc = wid & 1;
  int wm0 = wr * 32, wn0 = wc * 32;
  int p = lane >> 4, q = lane & 15;
  int r = tid >> 2, qt = tid & 3;
  int bn8 = tid & 63, bks = tid >> 6;
  int arow = bm + r;
  bool rok = arow < M;
  const float* ap = D.A + (size_t)arow * K + qt * 8;
  const float* qpp = nullptr;
  if (D.mode == 1) qpp = D.qp + (size_t)arow * 256 + qt * 8;
  else if (D.mode == 2) qpp = D.qp + (size_t)((arow / 1500) * 300 + (arow % 300)) * 256 + qt * 8;
  const unsigned short* bp = D.Wt + (size_t)(bn + bn8) * K;

  f4 areg[2];
  s16x8 breg;
  auto loadA = [&](int k0) {
    f4 z = {0.f, 0.f, 0.f, 0.f};
    if (rok) {
      areg[0] = *(const f4*)(ap + k0);
      areg[1] = *(const f4*)(ap + k0 + 4);
      if (qpp) {
        areg[0] += *(const f4*)(qpp + k0);
        areg[1] += *(const f4*)(qpp + k0 + 4);
      }
    } else { areg[0] = z; areg[1] = z; }
  };
  auto loadB = [&](int k0) {
    breg = *(const s16x8*)(bp + k0 + bks * 8);
  };
  auto stage = [&](int buf) {
    s16x8 c0;
#pragma unroll
    for (int j = 0; j < 4; ++j) { c0[j] = (short)f2bf(areg[0][j]); c0[j + 4] = (short)f2bf(areg[1][j]); }
    Als[buf][qt * BM + r] = c0;
    Bls[buf][bks * BN + bn8] = breg;
  };

  f32x4 acc[FM][FN] = {};
  int nk = K >> 5;
  loadA(0); loadB(0); stage(0);
  __syncthreads();
  for (int ks = 0; ks < nk; ++ks) {
    int cur = ks & 1;
    bool more = (ks + 1) < nk;
    if (more) { loadA((ks + 1) << 5); loadB((ks + 1) << 5); }
    s16x8 af[FM], bfr[FN];
#pragma unroll
    for (int i = 0; i < FM; ++i) af[i] = Als[cur][p * BM + wm0 + i * 16 + q];
#pragma unroll
    for (int j = 0; j < FN; ++j) bfr[j] = Bls[cur][p * BN + wn0 + j * 16 + q];
#pragma unroll
    for (int i = 0; i < FM; ++i)
#pragma unroll
      for (int j = 0; j < FN; ++j)
        acc[i][j] = __builtin_amdgcn_mfma_f32_16x16x32_bf16(af[i], bfr[j], acc[i][j], 0, 0, 0);
    if (more) stage(cur ^ 1);
    __syncthreads();
  }
  int p4 = p * 4;
#pragma unroll
  for (int i = 0; i < FM; ++i) {
#pragma unroll
    for (int rr = 0; rr < 4; ++rr) {
      int row = bm + wm0 + i * 16 + p4 + rr;
      if (row >= M) continue;
#pragma unroll
      for (int j = 0; j < FN; ++j) {
        int col = bn + wn0 + j * 16 + q;
        float v = acc[i][j][rr] + D.bias[col];
        if (D.relu) v = fmaxf(v, 0.0f);
        if (D.obf16)
          ((unsigned short*)D.C)[(size_t)row * D.ldc + col] = f2bf(v);
        else
          D.C[(size_t)row * D.ldc + col] = v;
      }
    }
  }
}

// ---------------------------------------------------------------------------
__launch_bounds__(256)
__global__ void add_ln_kernel(const float* __restrict__ a, const float* __restrict__ b,
                              const float* __restrict__ g, const float* __restrict__ be,
                              float* __restrict__ out)
{
  __shared__ float red[4];
  int row = blockIdx.x, c = threadIdx.x;
  size_t i = (size_t)row * 256 + c;
  float x = a[i] + b[i];
  float w = wave_sum(x);
  int wid = c >> 6;
  if ((c & 63) == 0) red[wid] = w;
  __syncthreads();
  float mean = (red[0] + red[1] + red[2] + red[3]) * (1.0f / 256.0f);
  float d = x - mean;
  __syncthreads();
  w = wave_sum(d * d);
  if ((c & 63) == 0) red[wid] = w;
  __syncthreads();
  float var = (red[0] + red[1] + red[2] + red[3]) * (1.0f / 256.0f);
  out[i] = d * rsqrtf(var + 1e-5f) * g[c] + be[c];
}

__launch_bounds__(256)
__global__ void add_ln2_kernel(const float* a0, const float* b0, const float* g0,
                               const float* be0, float* o0,
                               const float* a1, const float* b1, const float* g1,
                               const float* be1, float* o1, int m0)
{
  __shared__ float red[4];
  int row = blockIdx.x, c = threadIdx.x;
  const float *a, *b, *g, *be; float* out;
  if (row < m0) { a = a0; b = b0; g = g0; be = be0; out = o0; }
  else { row -= m0; a = a1; b = b1; g = g1; be = be1; out = o1; }
  size_t i = (size_t)row * 256 + c;
  float x = a[i] + b[i];
  float w = wave_sum(x);
  int wid = c >> 6;
  if ((c & 63) == 0) red[wid] = w;
  __syncthreads();
  float mean = (red[0] + red[1] + red[2] + red[3]) * (1.0f / 256.0f);
  float d = x - mean;
  __syncthreads();
  w = wave_sum(d * d);
  if ((c & 63) == 0) red[wid] = w;
  __syncthreads();
  float var = (red[0] + red[1] + red[2] + red[3]) * (1.0f / 256.0f);
  out[i] = d * rsqrtf(var + 1e-5f) * g[c] + be[c];
}

__launch_bounds__(256)
__global__ void add_ln_tw_kernel(const float* __restrict__ a, const float* __restrict__ b,
                                 const float* __restrict__ g, const float* __restrict__ be,
                                 const float* __restrict__ tw_w, const float* __restrict__ tw_b,
                                 float* __restrict__ out, float* __restrict__ tw_raw)
{
  __shared__ float red[4];
  int row = blockIdx.x, c = threadIdx.x;
  size_t i = (size_t)row * 256 + c;
  float x = a[i] + b[i];
  float w = wave_sum(x);
  int wid = c >> 6;
  if ((c & 63) == 0) red[wid] = w;
  __syncthreads();
  float mean = (red[0] + red[1] + red[2] + red[3]) * (1.0f / 256.0f);
  float d = x - mean;
  __syncthreads();
  w = wave_sum(d * d);
  if ((c & 63) == 0) red[wid] = w;
  __syncthreads();
  float var = (red[0] + red[1] + red[2] + red[3]) * (1.0f / 256.0f);
  float v = d * rsqrtf(var + 1e-5f) * g[c] + be[c];
  out[i] = v;
  __syncthreads();
  float tws = wave_sum(v * tw_w[c]);
  if ((c & 63) == 0) red[wid] = tws;
  __syncthreads();
  if (c == 0) tw_raw[row] = red[0] + red[1] + red[2] + red[3] + tw_b[0];
}

__launch_bounds__(256)
__global__ void tw_ln_kernel(const float* __restrict__ tw_raw, const float* __restrict__ t2c,
                             const float* __restrict__ cls_s, const float* __restrict__ g,
                             const float* __restrict__ be, float* __restrict__ out)
{
  __shared__ float red[4];
  int nq = blockIdx.x;
  int n = nq / 300, q = nq % 300;
  int c = threadIdx.x;
  float s[5], m = -1e30f;
#pragma unroll
  for (int f = 0; f < 5; ++f) { s[f] = tw_raw[(n * 5 + f) * 300 + q]; m = fmaxf(m, s[f]); }
  float sum = 0.f;
#pragma unroll
  for (int f = 0; f < 5; ++f) { s[f] = __expf(s[f] - m); sum += s[f]; }
  float inv = 1.0f / sum;
  float acc = 0.f;
#pragma unroll
  for (int f = 0; f < 5; ++f)
    acc += t2c[((size_t)(n * 5 + f) * 300 + q) * 256 + c] * s[f];
  float x = cls_s[(size_t)nq * 256 + c] + acc * inv;
  float w = wave_sum(x);
  int wid = c >> 6;
  if ((c & 63) == 0) red[wid] = w;
  __syncthreads();
  float mean = (red[0] + red[1] + red[2] + red[3]) * (1.0f / 256.0f);
  float d = x - mean;
  __syncthreads();
  w = wave_sum(d * d);
  if ((c & 63) == 0) red[wid] = w;
  __syncthreads();
  float var = (red[0] + red[1] + red[2] + red[3]) * (1.0f / 256.0f);
  out[(size_t)nq * 256 + c] = d * rsqrtf(var + 1e-5f) * g[c] + be[c];
}

// ---------------------------------------------------------------------------
// MFMA MHA; qkv is bf16 (written directly by the QKV GEMM). Q-scale folded
// into the f32 scores. Blocks 0..79 cls, 80..479 loc.
__launch_bounds__(256)
__global__ void attn_mfma_kernel(const unsigned short* __restrict__ qkv_c, float* __restrict__ out_c,
                                 const unsigned short* __restrict__ qkv_l, float* __restrict__ out_l)
{
  constexpr int L = 300, NKT = 19;
  __shared__ __align__(16) short Kf[NKT * 64 * 8];
  __shared__ __align__(16) short Vf[10 * 2 * 64 * 8];
  __shared__ __align__(16) short Pf[4][5 * 64 * 8];
  int bid = blockIdx.x;
  const unsigned short* qkv; float* out; int sub;
  if (bid < 80) { qkv = qkv_c; out = out_c; sub = bid; }
  else { qkv = qkv_l; out = out_l; sub = bid - 80; }
  int b = sub / 40;
  int h = (sub % 40) / 5;
  int band = sub % 5;
  int tid = threadIdx.x;
  int lane = tid & 63, w = tid >> 6;
  int c = lane & 15, sl = lane >> 4, jj = lane & 7;
  const unsigned short* base = qkv + (size_t)b * L * 768;

  {
    s16x8 z = {};
    for (int i = tid; i < 10 * 2 * 64; i += 256) *(s16x8*)&Vf[i * 8] = z;
  }
  // K staging: raw 16B copies (bf16 source), frag layout as before.
  for (int idx = tid; idx < 1200; idx += 256) {
    int key = idx >> 2, s = idx & 3;
    s16x8 kv = *(const s16x8*)(base + (size_t)key * 768 + 256 + h * 32 + s * 8);
    *(s16x8*)&Kf[(((key >> 4) * 64) + ((s << 4) | (key & 15))) * 8] = kv;
  }
  __syncthreads();  // V zero-fill visible before scatter
  for (int idx = tid; idx < 1200; idx += 256) {
    int key = idx >> 2, s = idx & 3;
    s16x8 vv = *(const s16x8*)(base + (size_t)key * 768 + 512 + h * 32 + s * 8);
    int bb = (((key >> 5) * 2 + (s >> 1)) * 64) * 8;
    int lane0 = (((key >> 3) & 3) << 4) | ((s & 1) * 8);
    int elem = key & 7;
#pragma unroll
    for (int j = 0; j < 8; ++j)
      Vf[bb + (lane0 + j) * 8 + elem] = vv[j];
  }
  int qloc = band * 64 + w * 16 + c;
  int qr = qloc < L ? qloc : L - 1;
  s16x8 qfrag = *(const s16x8*)(base + (size_t)qr * 768 + h * 32 + sl * 8);
  __syncthreads();

  f32x4 sc[NKT];
#pragma unroll
  for (int kt = 0; kt < NKT; ++kt) {
    s16x8 kfr = *(const s16x8*)&Kf[(kt * 64 + lane) * 8];
    f32x4 z = {};
    sc[kt] = __builtin_amdgcn_mfma_f32_16x16x32_bf16(qfrag, kfr, z, 0, 0, 0);
  }
  constexpr float kscale = 0.17677669529663687f;   // 1/sqrt(32), folded from Q
#pragma unroll
  for (int kt = 0; kt < NKT; ++kt)
#pragma unroll
    for (int r = 0; r < 4; ++r) sc[kt][r] *= kscale;
  if (c >= 12) {
#pragma unroll
    for (int r = 0; r < 4; ++r) sc[18][r] = -1e30f;
  }

  float inv[4];
#pragma unroll
  for (int r = 0; r < 4; ++r) {
    float m = sc[0][r];
#pragma unroll
    for (int kt = 1; kt < NKT; ++kt) m = fmaxf(m, sc[kt][r]);
#pragma unroll
    for (int o = 1; o < 16; o <<= 1) m = fmaxf(m, __shfl_xor(m, o, 64));
    float s = 0.f;
#pragma unroll
    for (int kt = 0; kt < NKT; ++kt) { float e = __expf(sc[kt][r] - m); sc[kt][r] = e; s += e; }
#pragma unroll
    for (int o = 1; o < 16; o <<= 1) s += __shfl_xor(s, o, 64);
    inv[r] = 1.0f / s;
  }

  f32x4 oacc[2] = {};
  short* Pw = &Pf[w][0];
#pragma unroll
  for (int ch = 0; ch < 2; ++ch) {
    int kt0 = ch * 10, kt1 = (ch == 0) ? 10 : NKT;
#pragma unroll
    for (int kt = kt0; kt < kt1; ++kt) {
      int t = (kt >> 1) - ch * 5;
      int slice = ((kt & 1) << 1) | (c >> 3);
#pragma unroll
      for (int r = 0; r < 4; ++r) {
        int qrow = sl * 4 + r;
        Pw[(t * 64 + (slice << 4) + qrow) * 8 + jj] = (short)f2bf(sc[kt][r] * inv[r]);
      }
    }
#pragma unroll
    for (int t = 0; t < 5; ++t) {
      s16x8 pfr = *(const s16x8*)&Pw[(t * 64 + lane) * 8];
#pragma unroll
      for (int dh = 0; dh < 2; ++dh) {
        s16x8 vfr = *(const s16x8*)&Vf[((((ch * 5 + t) * 2) + dh) * 64 + lane) * 8];
        oacc[dh] = __builtin_amdgcn_mfma_f32_16x16x32_bf16(pfr, vfr, oacc[dh], 0, 0, 0);
      }
    }
  }

#pragma unroll
  for (int r = 0; r < 4; ++r) {
    int qo = band * 64 + w * 16 + sl * 4 + r;
    if (qo < L) {
#pragma unroll
      for (int dh = 0; dh < 2; ++dh)
        out[((size_t)(b * L + qo)) * 256 + h * 32 + dh * 16 + c] = oacc[dh][r];
    }
  }
}

// ---------------------------------------------------------------------------
// MSDA bilinear sampling with folded per-head softmax; value is fp8 e4m3.
__launch_bounds__(256)
__global__ void msda_kernel(const float* __restrict__ offp, const float* __restrict__ awp,
                            const float* __restrict__ refp,
                            const unsigned char* __restrict__ value,
                            float* __restrict__ out)
{
  const int Hs[4] = {100, 50, 25, 13};
  const int Ws[4] = {150, 75, 38, 19};
  const int st[4] = {0, 15000, 18750, 19700};
  __shared__ float saw[128];
  int row = blockIdx.x;
  int b = row / 300;
  int tid = threadIdx.x;
  if (tid < 128) {
    float v = awp[(size_t)row * 128 + tid];
    float m = v;
#pragma unroll
    for (int o = 1; o < 16; o <<= 1) m = fmaxf(m, __shfl_xor(m, o, 16));
    float e = __expf(v - m);
    float s = e;
#pragma unroll
    for (int o = 1; o < 16; o <<= 1) s += __shfl_xor(s, o, 16);
    saw[tid] = e / s;
  }
  __syncthreads();
  int h = tid >> 5, d2 = tid & 31;
  const float* offr = offp + (size_t)row * 256 + h * 32;
  const float* awr = saw + h * 16;
  const float* rf = refp + (size_t)row * 8;
  const unsigned char* vb = value + (size_t)b * 19947 * 256;
  float acc = 0.f;
#pragma unroll
  for (int l = 0; l < 4; ++l) {
    int H = Hs[l], W = Ws[l];
    float rx = rf[l * 2 + 0], ry = rf[l * 2 + 1];
#pragma unroll
    for (int pp = 0; pp < 4; ++pp) {
      float ox = offr[l * 8 + pp * 2 + 0], oy = offr[l * 8 + pp * 2 + 1];
      float x = (rx + ox / (float)W) * (float)W - 0.5f;
      float y = (ry + oy / (float)H) * (float)H - 0.5f;
      float x0f = floorf(x), y0f = floorf(y);
      float wx = x - x0f, wy = y - y0f;
      int x0 = (int)x0f, y0 = (int)y0f;
      float aw = awr[l * 4 + pp];
      float sv = 0.f;
#pragma unroll
      for (int cy = 0; cy < 2; ++cy) {
#pragma unroll
        for (int cx = 0; cx < 2; ++cx) {
          int ix = x0 + cx, iy = y0 + cy;
          bool valid = (ix >= 0) && (ix < W) && (iy >= 0) && (iy < H);
          float gg = 0.f;
          if (valid) {
            int idx = iy * W + ix;
            gg = fp82f(vb[((size_t)(st[l] + idx)) * 256 + h * 32 + d2]);
          }
          float wgt = (cx ? wx : 1.f - wx) * (cy ? wy : 1.f - wy);
          sv += gg * wgt;
        }
      }
      acc += sv * aw;
    }
  }
  out[(size_t)row * 256 + tid] = acc;
}

// ---------------------------------------------------------------------------
struct GArg { const float* A; const unsigned short* Wt; const float* bias; float* C;
              const float* qp; int M, N, K, ldc, mode, relu, obf16; };

static void launch_group(hipStream_t st, const GArg* a, int n)
{
  GPack g; g.n = n;
  int blocks = 0;
  for (int i = 0; i < n; ++i) {
    GDesc& d = g.d[i];
    d.A = a[i].A; d.Wt = a[i].Wt; d.bias = a[i].bias; d.C = a[i].C; d.qp = a[i].qp;
    d.M = a[i].M; d.K = a[i].K; d.ldc = a[i].ldc; d.nNb = a[i].N / 64;
    d.mode = a[i].mode; d.relu = a[i].relu; d.obf16 = a[i].obf16; d.block0 = blocks;
    blocks += ((a[i].M + 63) / 64) * d.nNb;
  }
  for (int i = n; i < 4; ++i) g.d[i] = g.d[n - 1];
  gemm_group<<<blocks, 256, 0, st>>>(g);
}

extern "C" void kernel_launch(void* const* d_in, const int* in_sizes, int n_in,
                              void* d_out, int out_size, void* d_ws, size_t ws_size,
                              hipStream_t stream)
{
  const float* tgt_cls   = (const float*)d_in[0];
  const float* tgt_loc   = (const float*)d_in[1];
  const float* query_pos = (const float*)d_in[2];
  const float* refp      = (const float*)d_in[3];
  const float* src       = (const float*)d_in[4];
  const float* in_w_cls = (const float*)d_in[8];
  const float* in_b_cls = (const float*)d_in[9];
  const float* out_w_cls = (const float*)d_in[10];
  const float* out_b_cls = (const float*)d_in[11];
  const float* in_w_loc = (const float*)d_in[12];
  const float* in_b_loc = (const float*)d_in[13];
  const float* out_w_loc = (const float*)d_in[14];
  const float* out_b_loc = (const float*)d_in[15];
  const float* off_w = (const float*)d_in[16];
  const float* off_b = (const float*)d_in[17];
  const float* aw_w = (const float*)d_in[18];
  const float* aw_b = (const float*)d_in[19];
  const float* val_w = (const float*)d_in[20];
  const float* val_b = (const float*)d_in[21];
  const float* cow = (const float*)d_in[22];
  const float* cob = (const float*)d_in[23];
  const float* l1w_cls = (const float*)d_in[24];
  const float* l1b_cls = (const float*)d_in[25];
  const float* l2w_cls = (const float*)d_in[26];
  const float* l2b_cls = (const float*)d_in[27];
  const float* l1w_loc = (const float*)d_in[28];
  const float* l1b_loc = (const float*)d_in[29];
  const float* l2w_loc = (const float*)d_in[30];
  const float* l2b_loc = (const float*)d_in[31];
  const float* n1c_g = (const float*)d_in[32]; const float* n1c_b = (const float*)d_in[33];
  const float* n1l_g = (const float*)d_in[34]; const float* n1l_b = (const float*)d_in[35];
  const float* n2c_g = (const float*)d_in[36]; const float* n2c_b = (const float*)d_in[37];
  const float* n2l_g = (const float*)d_in[38]; const float* n2l_b = (const float*)d_in[39];
  const float* n3c_g = (const float*)d_in[40]; const float* n3c_b = (const float*)d_in[41];
  const float* n3l_g = (const float*)d_in[42]; const float* n3l_b = (const float*)d_in[43];
  const float* tw_w = (const float*)d_in[44];  const float* tw_b = (const float*)d_in[45];

  float* out_cls = (float*)d_out;            // (2,300,256)
  float* out_loc = (float*)d_out + 153600;   // (2,5,300,256)

  char* w = (char*)d_ws;
  size_t o = 0;
  auto F = [&](size_t n) -> float* {
    float* p = (float*)(w + o);
    o += ((n * 4 + 255) & ~(size_t)255);
    return p;
  };
  auto B16 = [&](size_t n) -> unsigned short* {
    unsigned short* p = (unsigned short*)(w + o);
    o += ((n * 2 + 255) & ~(size_t)255);
    return p;
  };
  auto B8 = [&](size_t n) -> unsigned char* {
    unsigned char* p = (unsigned char*)(w + o);
    o += ((n + 255) & ~(size_t)255);
    return p;
  };
  unsigned short* qkv_c = B16(600 * 768);    // bf16 QKV
  float* attno_c = F(600 * 256);
  float* t2_c    = F(600 * 256);
  float* cls_s   = F(600 * 256);
  float* cls_mid = F(600 * 256);
  float* hc1     = F(600 * 1024);
  float* hc2     = F(600 * 256);
  unsigned short* qkv_l = B16(3000 * 768);   // bf16 QKV
  float* attno_l = F(3000 * 256);
  float* t2l     = F(3000 * 256);
  float* loc_s   = F(3000 * 256);
  float* offp    = F(3000 * 256);
  float* awp     = F(3000 * 128);
  float* samp    = F(3000 * 256);
  float* t2c     = F(3000 * 256);
  float* loc_o   = F(3000 * 256);
  float* h1      = F(3000 * 1024);
  float* h2      = F(3000 * 256);
  float* tw_raw  = F(3000);
  unsigned char* value = B8((size_t)199470 * 256);   // fp8 e4m3
  unsigned short* wt_in_cls  = B16(768 * 256);
  unsigned short* wt_in_loc  = B16(768 * 256);
  unsigned short* wt_out_cls = B16(256 * 256);
  unsigned short* wt_out_loc = B16(256 * 256);
  unsigned short* wt_off     = B16(256 * 256);
  unsigned short* wt_aw      = B16(128 * 256);
  unsigned short* wv3        = B16(256 * 256);   // K-step LDS-image layout
  unsigned short* wt_cow     = B16(256 * 256);
  unsigned short* wt_l1_cls  = B16(1024 * 256);
  unsigned short* wt_l2_cls  = B16(256 * 1024);
  unsigned short* wt_l1_loc  = B16(1024 * 256);
  unsigned short* wt_l2_loc  = B16(256 * 1024);

  // ---- 1. Weight transpose+convert (+val_w reorder tail) ----
  TPack tp;
  auto TE = [](const float* s, unsigned short* d, int K, int N) { TDesc t; t.src = s; t.dst = d; t.K = K; t.N = N; t.tile0 = 0; return t; };
  tp.d[0]  = TE(in_w_cls, wt_in_cls, 256, 768);
  tp.d[1]  = TE(in_w_loc, wt_in_loc, 256, 768);
  tp.d[2]  = TE(out_w_cls, wt_out_cls, 256, 256);
  tp.d[3]  = TE(out_w_loc, wt_out_loc, 256, 256);
  tp.d[4]  = TE(off_w, wt_off, 256, 256);
  tp.d[5]  = TE(aw_w, wt_aw, 256, 128);
  tp.d[6]  = TE(cow, wt_cow, 256, 256);
  tp.d[7]  = TE(l1w_cls, wt_l1_cls, 256, 1024);
  tp.d[8]  = TE(l2w_cls, wt_l2_cls, 1024, 256);
  tp.d[9]  = TE(l1w_loc, wt_l1_loc, 256, 1024);
  tp.d[10] = TE(l2w_loc, wt_l2_loc, 1024, 256);
  tp.d[11] = TE(l2w_loc, wt_l2_loc, 1024, 256);  // dummy (never selected first)
  int tiles = 0;
  for (int i = 0; i < 11; ++i) { tp.d[i].tile0 = tiles; tiles += (tp.d[i].K >> 5) * (tp.d[i].N >> 5); }
  tp.d[11].tile0 = tiles - (tp.d[10].K >> 5) * (tp.d[10].N >> 5);
  tp.rtile0 = tiles; tp.rW = val_w; tp.rB3 = wv3;
  transpose_cvt_kernel<<<tiles + 256, 256, 0, stream>>>(tp);

  // ---- 2. Value projection (dominant; launch early) ----
  gemm_val<<<(199470 + 63) / 64, 256, 0, stream>>>(src, wv3, val_b, value);

  // ---- 3. QKV projections for cls+loc (adds folded in; bf16 out) ----
  {
    GArg a[4] = {
      {tgt_cls, wt_in_cls,             in_b_cls,       (float*)qkv_c,         query_pos, 600, 512, 256, 768, 1, 0, 1},
      {tgt_cls, wt_in_cls + 512 * 256, in_b_cls + 512, (float*)(qkv_c + 512), nullptr,   600, 256, 256, 768, 0, 0, 1},
      {tgt_loc, wt_in_loc,             in_b_loc,       (float*)qkv_l,         query_pos, 3000, 512, 256, 768, 2, 0, 1},
      {tgt_loc, wt_in_loc + 512 * 256, in_b_loc + 512, (float*)(qkv_l + 512), nullptr,   3000, 256, 256, 768, 0, 0, 1},
    };
    launch_group(stream, a, 4);
  }
  // ---- 4. Both self-attentions ----
  attn_mfma_kernel<<<480, 256, 0, stream>>>(qkv_c, attno_c, qkv_l, attno_l);
  // ---- 5. Output projections ----
  {
    GArg a[2] = {
      {attno_c, wt_out_cls, out_b_cls, t2_c, nullptr, 600, 256, 256, 256, 0, 0, 0},
      {attno_l, wt_out_loc, out_b_loc, t2l,  nullptr, 3000, 256, 256, 256, 0, 0, 0},
    };
    launch_group(stream, a, 2);
  }
  // ---- 6. Post-attention LayerNorms ----
  add_ln2_kernel<<<3600, 256, 0, stream>>>(tgt_cls, t2_c, n2c_g, n2c_b, cls_s,
                                           tgt_loc, t2l, n2l_g, n2l_b, loc_s, 600);
  // ---- 7. Offset + attention-weight projections (query add folded) ----
  {
    GArg a[2] = {
      {loc_s, wt_off, off_b, offp, query_pos, 3000, 256, 256, 256, 2, 0, 0},
      {loc_s, wt_aw,  aw_b,  awp,  query_pos, 3000, 128, 256, 128, 2, 0, 0},
    };
    launch_group(stream, a, 2);
  }
  // ---- 8. MSDA sampling ----
  msda_kernel<<<3000, 256, 0, stream>>>(offp, awp, refp, value, samp);
  // ---- 9. Cross output projection ----
  {
    GArg a[1] = {{samp, wt_cow, cob, t2c, nullptr, 3000, 256, 256, 256, 0, 0, 0}};
    launch_group(stream, a, 1);
  }
  // ---- 10. LN (n1l) ----
  add_ln_kernel<<<3000, 256, 0, stream>>>(loc_s, t2c, n1l_g, n1l_b, loc_o);
  // ---- 11-12. loc FFN ----
  {
    GArg a[1] = {{loc_o, wt_l1_loc, l1b_loc, h1, nullptr, 3000, 1024, 256, 1024, 0, 1, 0}};
    launch_group(stream, a, 1);
  }
  {
    GArg a[1] = {{h1, wt_l2_loc, l2b_loc, h2, nullptr, 3000, 256, 1024, 256, 0, 0, 0}};
    launch_group(stream, a, 1);
  }
  // ---- 13. LN (n3l) -> out_loc, fused temporal dot ----
  add_ln_tw_kernel<<<3000, 256, 0, stream>>>(loc_o, h2, n3l_g, n3l_b, tw_w, tw_b,
                                             out_loc, tw_raw);
  // ---- 14. temporal softmax+combine + LN (n1c) -> cls_mid ----
  tw_ln_kernel<<<600, 256, 0, stream>>>(tw_raw, t2c, cls_s, n1c_g, n1c_b, cls_mid);
  // ---- 15-16. cls FFN ----
  {
    GArg a[1] = {{cls_mid, wt_l1_cls, l1b_cls, hc1, nullptr, 600, 1024, 256, 1024, 0, 1, 0}};
    launch_group(stream, a, 1);
  }
  {
    GArg a[1] = {{hc1, wt_l2_cls, l2b_cls, hc2, nullptr, 600, 256, 1024, 256, 0, 0, 0}};
    launch_group(stream, a, 1);
  }
  // ---- 17. LN (n3c) -> out_cls ----
  add_ln_kernel<<<600, 256, 0, stream>>>(cls_mid, hc2, n3c_g, n3c_b, out_cls);
}